// Round 1
// baseline (1100.357 us; speedup 1.0000x reference)
//
#include <hip/hip_runtime.h>
#include <cstdint>
#include <cstddef>

// Problem constants (from reference): [B,H,N,Dh] = [4,16,2048,64]
#define B_   4
#define H_   16
#define N_   2048
#define D_   64
#define BH_  (B_ * H_)
#define TS   64              // tile size (rows and cols)
#define LDST (TS + 4)        // LDS leading-dim pad: 68 floats = 272 B, keeps float4 16B-aligned
#define SCALE 0.125f         // (1024/16)^-0.5

// ---------------------------------------------------------------------------
// Pass 1: rinv[bh,n] = 1 / sum_m exp(SCALE * q_n . k_m)
// One workgroup = one (bh, 64-row tile); streams all K tiles.
// ---------------------------------------------------------------------------
__global__ __launch_bounds__(256)
void mha_rowsum(const float* __restrict__ q, const float* __restrict__ k,
                float* __restrict__ rinv)
{
    __shared__ float QT[D_][LDST];   // transposed Q tile: QT[d][n]
    __shared__ float KT[D_][LDST];   // transposed K tile: KT[d][m]
    __shared__ float red[TS][17];    // row-sum reduction scratch

    const int t  = threadIdx.x;
    const int wg = blockIdx.x;
    const int ntiles = N_ / TS;              // 32
    const int bh = wg / ntiles;
    const int nt = wg % ntiles;

    const float* Qg = q + (size_t)bh * N_ * D_ + (size_t)nt * TS * D_;
    const float* Kg = k + (size_t)bh * N_ * D_;

    // Stage Q tile transposed (coalesced global read, scattered LDS write)
    #pragma unroll
    for (int i = 0; i < 16; ++i) {
        int idx = i * 256 + t;               // flat n*64+d
        int n = idx >> 6, d = idx & 63;
        QT[d][n] = Qg[idx];
    }

    const int tx = t & 15, ty = t >> 4;      // thread computes rows 4*ty.., cols 4*tx..
    float accr[4] = {0.f, 0.f, 0.f, 0.f};

    for (int mt = 0; mt < ntiles; ++mt) {
        __syncthreads();                     // protect KT (and QT on first iter)
        #pragma unroll
        for (int i = 0; i < 16; ++i) {
            int idx = i * 256 + t;
            int m = idx >> 6, d = idx & 63;
            KT[d][m] = Kg[(size_t)mt * TS * D_ + idx];
        }
        __syncthreads();

        float c[4][4] = {};
        #pragma unroll
        for (int d = 0; d < D_; ++d) {
            float4 qa = *(const float4*)&QT[d][4 * ty];
            float4 ka = *(const float4*)&KT[d][4 * tx];
            c[0][0] += qa.x * ka.x; c[0][1] += qa.x * ka.y; c[0][2] += qa.x * ka.z; c[0][3] += qa.x * ka.w;
            c[1][0] += qa.y * ka.x; c[1][1] += qa.y * ka.y; c[1][2] += qa.y * ka.z; c[1][3] += qa.y * ka.w;
            c[2][0] += qa.z * ka.x; c[2][1] += qa.z * ka.y; c[2][2] += qa.z * ka.z; c[2][3] += qa.z * ka.w;
            c[3][0] += qa.w * ka.x; c[3][1] += qa.w * ka.y; c[3][2] += qa.w * ka.z; c[3][3] += qa.w * ka.w;
        }
        #pragma unroll
        for (int i = 0; i < 4; ++i) {
            #pragma unroll
            for (int j = 0; j < 4; ++j)
                accr[i] += __expf(c[i][j] * SCALE);
        }
    }

    // Reduce the 16 column-partials (across tx) per row
    #pragma unroll
    for (int i = 0; i < 4; ++i) red[4 * ty + i][tx] = accr[i];
    __syncthreads();
    if (t < TS) {
        float s = 0.f;
        #pragma unroll
        for (int j = 0; j < 16; ++j) s += red[t][j];
        rinv[(size_t)bh * N_ + (size_t)nt * TS + t] = 1.0f / s;
    }
}

// ---------------------------------------------------------------------------
// Pass 2: colsum[m] = sum_n exp(SCALE * q_n . k_m) * rinv[n]
//         out[bh,m,d] = colsum[m] * v[bh,m,d]
// One workgroup = one (bh, 64-col tile); streams all Q tiles.
// ---------------------------------------------------------------------------
__global__ __launch_bounds__(256)
void mha_colsum(const float* __restrict__ q, const float* __restrict__ k,
                const float* __restrict__ v, const float* __restrict__ rinv,
                float* __restrict__ out)
{
    __shared__ float KT[D_][LDST];   // fixed col (key) tile
    __shared__ float QT[D_][LDST];   // streamed row (query) tile
    __shared__ float rv[TS];
    __shared__ float red[16][TS];    // [ty][col]
    __shared__ float cs[TS];

    const int t  = threadIdx.x;
    const int wg = blockIdx.x;
    const int mtiles = N_ / TS;
    const int bh = wg / mtiles;
    const int mt = wg % mtiles;

    const float* Qg = q + (size_t)bh * N_ * D_;
    const float* Kg = k + (size_t)bh * N_ * D_ + (size_t)mt * TS * D_;
    const float* Vg = v + (size_t)bh * N_ * D_ + (size_t)mt * TS * D_;
    const float* Rg = rinv + (size_t)bh * N_;

    #pragma unroll
    for (int i = 0; i < 16; ++i) {
        int idx = i * 256 + t;
        int m = idx >> 6, d = idx & 63;
        KT[d][m] = Kg[idx];
    }

    const int tx = t & 15, ty = t >> 4;
    float accc[4] = {0.f, 0.f, 0.f, 0.f};   // partial colsums for cols 4*tx..4*tx+3

    for (int nt2 = 0; nt2 < mtiles; ++nt2) {
        __syncthreads();
        #pragma unroll
        for (int i = 0; i < 16; ++i) {
            int idx = i * 256 + t;
            int n = idx >> 6, d = idx & 63;
            QT[d][n] = Qg[(size_t)nt2 * TS * D_ + idx];
        }
        if (t < TS) rv[t] = Rg[nt2 * TS + t];
        __syncthreads();

        float c[4][4] = {};
        #pragma unroll
        for (int d = 0; d < D_; ++d) {
            float4 qa = *(const float4*)&QT[d][4 * ty];
            float4 ka = *(const float4*)&KT[d][4 * tx];
            c[0][0] += qa.x * ka.x; c[0][1] += qa.x * ka.y; c[0][2] += qa.x * ka.z; c[0][3] += qa.x * ka.w;
            c[1][0] += qa.y * ka.x; c[1][1] += qa.y * ka.y; c[1][2] += qa.y * ka.z; c[1][3] += qa.y * ka.w;
            c[2][0] += qa.z * ka.x; c[2][1] += qa.z * ka.y; c[2][2] += qa.z * ka.z; c[2][3] += qa.z * ka.w;
            c[3][0] += qa.w * ka.x; c[3][1] += qa.w * ka.y; c[3][2] += qa.w * ka.z; c[3][3] += qa.w * ka.w;
        }

        const float r0 = rv[4 * ty + 0];
        const float r1 = rv[4 * ty + 1];
        const float r2 = rv[4 * ty + 2];
        const float r3 = rv[4 * ty + 3];
        #pragma unroll
        for (int j = 0; j < 4; ++j) {
            accc[j] += __expf(c[0][j] * SCALE) * r0
                     + __expf(c[1][j] * SCALE) * r1
                     + __expf(c[2][j] * SCALE) * r2
                     + __expf(c[3][j] * SCALE) * r3;
        }
    }

    // Reduce across ty (16 row-groups) for each column
    #pragma unroll
    for (int j = 0; j < 4; ++j) red[ty][4 * tx + j] = accc[j];
    __syncthreads();
    if (t < TS) {
        float s = 0.f;
        #pragma unroll
        for (int i = 0; i < 16; ++i) s += red[i][t];
        cs[t] = s;
    }
    __syncthreads();

    // out[m][d] = colsum[m] * v[m][d]
    float* Og = out + (size_t)bh * N_ * D_ + (size_t)mt * TS * D_;
    #pragma unroll
    for (int i = 0; i < 16; ++i) {
        int idx = i * 256 + t;
        int m = idx >> 6;
        Og[idx] = cs[m] * Vg[idx];
    }
}

// ---------------------------------------------------------------------------
extern "C" void kernel_launch(void* const* d_in, const int* in_sizes, int n_in,
                              void* d_out, int out_size, void* d_ws, size_t ws_size,
                              hipStream_t stream)
{
    const float* q = (const float*)d_in[0];
    const float* k = (const float*)d_in[1];
    const float* v = (const float*)d_in[2];
    float* out  = (float*)d_out;
    float* rinv = (float*)d_ws;          // BH_*N_ floats = 512 KB, fully written by pass 1

    const int ntiles = N_ / TS;          // 32
    dim3 grid(BH_ * ntiles);             // 2048 workgroups
    dim3 block(256);

    mha_rowsum<<<grid, block, 0, stream>>>(q, k, rinv);
    mha_colsum<<<grid, block, 0, stream>>>(q, k, v, rinv, out);
}

// Round 2
// 153.921 us; speedup vs baseline: 7.1488x; 7.1488x over previous
//
#include <hip/hip_runtime.h>
#include <cstdint>
#include <cstddef>

// [B,H,N,Dh] = [4,16,2048,64]; out[b,h,m,d] = (sum_n softmax(QK^T)[n,m]) * v[b,h,m,d]
#define B_    4
#define H_    16
#define N_    2048
#define D_    64
#define BH_   (B_*H_)
#define SCALE 0.125f
#define BT    128            // panel size (rows or cols) per workgroup
#define NTIL  (N_/BT)        // 16 streamed tiles

typedef __attribute__((ext_vector_type(8))) short bf16x8;   // 8 bf16 = 4 VGPR (MFMA A/B frag)
typedef __attribute__((ext_vector_type(4))) float f32x4;    // MFMA C/D frag

__device__ __forceinline__ short f2bf(float f) {
    union { float f; unsigned u; } x; x.f = f;
    unsigned r = x.u + 0x7FFF + ((x.u >> 16) & 1);          // RNE
    return (short)(r >> 16);
}

__device__ __forceinline__ bf16x8 cvt8(const float* p) {
    float4 a = *(const float4*)p;
    float4 b = *(const float4*)(p + 4);
    bf16x8 r;
    r[0] = f2bf(a.x); r[1] = f2bf(a.y); r[2] = f2bf(a.z); r[3] = f2bf(a.w);
    r[4] = f2bf(b.x); r[5] = f2bf(b.y); r[6] = f2bf(b.z); r[7] = f2bf(b.w);
    return r;
}

// Stage a 128-row x 64-d fp32 panel into bf16 LDS.
// LDS layout: row stride 128 B; eight 16 B chunks per row, chunk index XOR'd
// with (row&7) -> conflict-free ds_write_b128 and ds_read_b128 (G4 swizzle).
__device__ __forceinline__ void stage_tile(char* lds, const float* src, int t) {
    #pragma unroll
    for (int i = 0; i < 2; ++i) {
        int ch = i * 512 + t;                // 1024 chunks = 128 rows x 8
        int r = ch >> 3, cc = ch & 7;
        bf16x8 v = cvt8(src + (size_t)r * D_ + cc * 8);
        *(bf16x8*)(lds + r * 128 + ((cc ^ (r & 7)) << 4)) = v;
    }
}

__device__ __forceinline__ bf16x8 read_frag(const char* lds, int row, int cc) {
    return *(const bf16x8*)(lds + row * 128 + ((cc ^ (row & 7)) << 4));
}

// ---------------------------------------------------------------------------
// Pass 1: rinv[bh,n] = 1 / sum_m exp(SCALE * q_n . k_m)
// Workgroup: (bh, 128 Q rows). 8 waves x 16 rows. K streamed via LDS.
// ---------------------------------------------------------------------------
__global__ __launch_bounds__(512)
void mha_rowsum(const float* __restrict__ q, const float* __restrict__ k,
                float* __restrict__ rinv)
{
    __shared__ __align__(16) char KT[BT * 128];

    const int t = threadIdx.x;
    const int w = t >> 6, l = t & 63;
    const int bh = blockIdx.x / NTIL;
    const int rb = blockIdx.x % NTIL;

    const float* Qg = q + (size_t)bh * N_ * D_;
    const float* Kg = k + (size_t)bh * N_ * D_;

    // Fixed A-operand: wave's 16 Q rows, held in registers.
    // A frag: lane holds row (l&15), k = kh*32 + (l>>4)*8 + 0..7 (8 contiguous).
    const int qrow = rb * BT + w * 16 + (l & 15);
    bf16x8 af[2];
    #pragma unroll
    for (int kh = 0; kh < 2; ++kh)
        af[kh] = cvt8(Qg + (size_t)qrow * D_ + kh * 32 + (l >> 4) * 8);

    float rs[4] = {0.f, 0.f, 0.f, 0.f};

    for (int ct = 0; ct < NTIL; ++ct) {
        __syncthreads();
        stage_tile(KT, Kg + (size_t)ct * BT * D_, t);
        __syncthreads();

        #pragma unroll
        for (int cj = 0; cj < 8; ++cj) {
            const int krow = cj * 16 + (l & 15);   // B frag: lane's col = K row
            f32x4 c = {0.f, 0.f, 0.f, 0.f};
            #pragma unroll
            for (int kh = 0; kh < 2; ++kh) {
                bf16x8 bf = read_frag(KT, krow, kh * 4 + (l >> 4));
                c = __builtin_amdgcn_mfma_f32_16x16x32_bf16(af[kh], bf, c, 0, 0, 0);
            }
            rs[0] += __expf(c[0] * SCALE);
            rs[1] += __expf(c[1] * SCALE);
            rs[2] += __expf(c[2] * SCALE);
            rs[3] += __expf(c[3] * SCALE);
        }
    }

    // Reduce across the 16 col-lanes (l&15); D-row = (l>>4)*4 + reg.
    #pragma unroll
    for (int i = 0; i < 4; ++i) {
        rs[i] += __shfl_xor(rs[i], 1);
        rs[i] += __shfl_xor(rs[i], 2);
        rs[i] += __shfl_xor(rs[i], 4);
        rs[i] += __shfl_xor(rs[i], 8);
    }
    if ((l & 15) == 0) {
        const int rbase = rb * BT + w * 16 + (l >> 4) * 4;
        #pragma unroll
        for (int i = 0; i < 4; ++i)
            rinv[(size_t)bh * N_ + rbase + i] = 1.0f / rs[i];
    }
}

// ---------------------------------------------------------------------------
// Pass 2: colsum[m] = sum_n exp(SCALE * q_n . k_m) * rinv[n];
//         out[bh,m,d] = colsum[m] * v[bh,m,d]
// Workgroup: (bh, 128 K cols). 8 waves x 16 cols. Q streamed via LDS.
// ---------------------------------------------------------------------------
__global__ __launch_bounds__(512)
void mha_colsum(const float* __restrict__ q, const float* __restrict__ k,
                const float* __restrict__ v, const float* __restrict__ rinv,
                float* __restrict__ out)
{
    __shared__ __align__(16) char QT[BT * 128];
    __shared__ float rv[BT];
    __shared__ float cs[BT];

    const int t = threadIdx.x;
    const int w = t >> 6, l = t & 63;
    const int bh = blockIdx.x / NTIL;
    const int cb = blockIdx.x % NTIL;

    const float* Qg = q + (size_t)bh * N_ * D_;
    const float* Kg = k + (size_t)bh * N_ * D_;
    const float* Rg = rinv + (size_t)bh * N_;

    // Fixed B-operand: wave's 16 K cols in registers.
    const int kcol = cb * BT + w * 16 + (l & 15);
    bf16x8 kf[2];
    #pragma unroll
    for (int kh = 0; kh < 2; ++kh)
        kf[kh] = cvt8(Kg + (size_t)kcol * D_ + kh * 32 + (l >> 4) * 8);

    float ca = 0.f;   // partial colsum for col kcol

    for (int rt = 0; rt < NTIL; ++rt) {
        __syncthreads();
        stage_tile(QT, Qg + (size_t)rt * BT * D_, t);
        if (t < BT) rv[t] = Rg[rt * BT + t];
        __syncthreads();

        #pragma unroll
        for (int rj = 0; rj < 8; ++rj) {
            const int qr = rj * 16 + (l & 15);     // A frag: lane's row
            f32x4 c = {0.f, 0.f, 0.f, 0.f};
            #pragma unroll
            for (int kh = 0; kh < 2; ++kh) {
                bf16x8 a = read_frag(QT, qr, kh * 4 + (l >> 4));
                c = __builtin_amdgcn_mfma_f32_16x16x32_bf16(a, kf[kh], c, 0, 0, 0);
            }
            // D-row = rj*16 + (l>>4)*4 + reg -> rinv via broadcast float4 read
            float4 r4 = *(const float4*)&rv[rj * 16 + (l >> 4) * 4];
            ca += __expf(c[0] * SCALE) * r4.x
                + __expf(c[1] * SCALE) * r4.y
                + __expf(c[2] * SCALE) * r4.z
                + __expf(c[3] * SCALE) * r4.w;
        }
    }

    // Butterfly across the 4 row-groups -> every lane holds colsum for col (l&15).
    ca += __shfl_xor(ca, 16);
    ca += __shfl_xor(ca, 32);
    if (l < 16) cs[w * 16 + l] = ca;
    __syncthreads();

    // out[m][d] = colsum[m] * v[m][d]  (128 rows x 64 d, float4-vectorized)
    const float4* Vg = (const float4*)(v + (size_t)bh * N_ * D_ + (size_t)cb * BT * D_);
    float4* Og = (float4*)(out + (size_t)bh * N_ * D_ + (size_t)cb * BT * D_);
    #pragma unroll
    for (int i = 0; i < 4; ++i) {
        int id = i * 512 + t;                // 2048 float4 units
        int m = id >> 4;
        float4 vv = Vg[id];
        float s = cs[m];
        float4 o; o.x = vv.x * s; o.y = vv.y * s; o.z = vv.z * s; o.w = vv.w * s;
        Og[id] = o;
    }
}

// ---------------------------------------------------------------------------
extern "C" void kernel_launch(void* const* d_in, const int* in_sizes, int n_in,
                              void* d_out, int out_size, void* d_ws, size_t ws_size,
                              hipStream_t stream)
{
    const float* q = (const float*)d_in[0];
    const float* k = (const float*)d_in[1];
    const float* v = (const float*)d_in[2];
    float* out  = (float*)d_out;
    float* rinv = (float*)d_ws;              // BH_*N_ floats = 512 KB

    dim3 grid(BH_ * NTIL);                   // 64 bh x 16 panels = 1024 wgs
    dim3 block(512);

    mha_rowsum<<<grid, block, 0, stream>>>(q, k, rinv);
    mha_colsum<<<grid, block, 0, stream>>>(q, k, v, rinv, out);
}

// Round 5
// 108.423 us; speedup vs baseline: 10.1488x; 1.4196x over previous
//
#include <hip/hip_runtime.h>
#include <cstdint>
#include <cstddef>

// [B,H,N,Dh] = [4,16,2048,64]; out[b,h,m,d] = (sum_n softmax(QK^T)[n,m]) * v[b,h,m,d]
#define B_    4
#define H_    16
#define N_    2048
#define D_    64
#define BH_   (B_*H_)
#define SCALE 0.125f
#define QSCL  0.18033688011f      // SCALE * log2(e)

#define P_    256                 // fixed panel (rows in pass1 / cols in pass2) per wg
#define T_    128                 // streamed LDS tile rows
#define NT    (N_/T_)             // 16
#define NP    (N_/P_)             // 8
#define TILEB 16384               // bytes per bf16 tile: 128 rows x 128 B
#define BHB   (NT*TILEB)          // 256 KB per (bh, tensor)

typedef __attribute__((ext_vector_type(8))) short bf16x8;
typedef __attribute__((ext_vector_type(4))) float f32x4;

#if __has_builtin(__builtin_amdgcn_exp2f)
#define EXP2(x) __builtin_amdgcn_exp2f(x)
#else
#define EXP2(x) exp2f(x)
#endif

__device__ __forceinline__ short f2bf(float f) {
    union { float f; unsigned u; } x; x.f = f;
    unsigned r = x.u + 0x7FFF + ((x.u >> 16) & 1);  // RNE
    return (short)(r >> 16);
}

// byte offset of chunk (row, cc) inside a (bh, tensor) panel; XOR-swizzled so
// 16-row-stride ds_read_b128 is bank-conflict-free (G4)
__device__ __forceinline__ size_t swz(int row, int cc) {
    return ((size_t)(row >> 7) * TILEB) + ((row & 127) << 7) + ((cc ^ (row & 7)) << 4);
}

// ---------------------------------------------------------------------------
// Pre-pass: qk[] = [ Q' (bf16, x QSCL, swizzled image) | K' (bf16, swizzled) ]
// ---------------------------------------------------------------------------
__global__ __launch_bounds__(512)
void mha_convert(const float* __restrict__ q, const float* __restrict__ k,
                 char* __restrict__ qk)
{
    const int gid = blockIdx.x * 512 + threadIdx.x;     // 2*64*16384 chunks
    const int half = BH_ * N_ * 8;
    const bool isq = gid < half;
    const float* src = isq ? q : k;
    const float scl = isq ? QSCL : 1.0f;
    char* dst = qk + (isq ? 0 : (size_t)BH_ * BHB);
    const int id = isq ? gid : gid - half;
    const int bh  = id >> 14;            // 16384 chunks per bh
    const int row = (id >> 3) & 2047;
    const int cc  = id & 7;
    const float* p = src + ((size_t)bh * N_ + row) * D_ + cc * 8;
    float4 a = *(const float4*)p;
    float4 b = *(const float4*)(p + 4);
    bf16x8 o;
    o[0] = f2bf(a.x * scl); o[1] = f2bf(a.y * scl);
    o[2] = f2bf(a.z * scl); o[3] = f2bf(a.w * scl);
    o[4] = f2bf(b.x * scl); o[5] = f2bf(b.y * scl);
    o[6] = f2bf(b.z * scl); o[7] = f2bf(b.w * scl);
    *(bf16x8*)(dst + (size_t)bh * BHB + swz(row, cc)) = o;
}

// ---------------------------------------------------------------------------
// Pass 1: rinv[bh,n] = 1 / sum_m 2^(q'_n . k'_m)
// wg = (bh, 256-row panel); 8 waves x 32 rows; K' streamed via 16 KB LDS tile.
// ---------------------------------------------------------------------------
__global__ __launch_bounds__(512)
void mha_rowsum2(const char* __restrict__ qk, float* __restrict__ rinv)
{
    __shared__ __align__(16) char KT[TILEB];

    const int t = threadIdx.x, w = t >> 6, l = t & 63;
    const int wid = (blockIdx.x & 7) * 64 + (blockIdx.x >> 3);  // XCD swizzle (512%8==0)
    const int bh = wid / NP, rb = wid % NP;

    const char* Qp = qk + (size_t)bh * BHB;
    const char* Kp = qk + (size_t)BH_ * BHB + (size_t)bh * BHB;

    // Fixed A frags: rows rb*256 + w*32 + rg*16 + (l&15); chunk kh*4+(l>>4)
    bf16x8 af[2][2];
    #pragma unroll
    for (int rg = 0; rg < 2; ++rg)
        #pragma unroll
        for (int kh = 0; kh < 2; ++kh) {
            int row = rb * P_ + w * 32 + rg * 16 + (l & 15);
            af[rg][kh] = *(const bf16x8*)(Qp + swz(row, kh * 4 + (l >> 4)));
        }

    float rs[2][4] = {};

    for (int ct = 0; ct < NT; ++ct) {
        __syncthreads();
        const char* src = Kp + (size_t)ct * TILEB;     // tile is contiguous: linear copy
        *(bf16x8*)(KT + t * 16)        = *(const bf16x8*)(src + t * 16);
        *(bf16x8*)(KT + 8192 + t * 16) = *(const bf16x8*)(src + 8192 + t * 16);
        __syncthreads();

        #pragma unroll
        for (int cj = 0; cj < 8; ++cj) {
            const int krow = cj * 16 + (l & 15);
            const int kb = (krow & 127) << 7;
            bf16x8 b0 = *(const bf16x8*)(KT + kb + (((l >> 4) ^ (krow & 7)) << 4));
            bf16x8 b1 = *(const bf16x8*)(KT + kb + (((4 + (l >> 4)) ^ (krow & 7)) << 4));
            #pragma unroll
            for (int rg = 0; rg < 2; ++rg) {
                f32x4 c = {0.f, 0.f, 0.f, 0.f};
                c = __builtin_amdgcn_mfma_f32_16x16x32_bf16(af[rg][0], b0, c, 0, 0, 0);
                c = __builtin_amdgcn_mfma_f32_16x16x32_bf16(af[rg][1], b1, c, 0, 0, 0);
                rs[rg][0] += EXP2(c[0]);
                rs[rg][1] += EXP2(c[1]);
                rs[rg][2] += EXP2(c[2]);
                rs[rg][3] += EXP2(c[3]);
            }
        }
    }

    #pragma unroll
    for (int rg = 0; rg < 2; ++rg)
        #pragma unroll
        for (int i = 0; i < 4; ++i) {
            rs[rg][i] += __shfl_xor(rs[rg][i], 1);
            rs[rg][i] += __shfl_xor(rs[rg][i], 2);
            rs[rg][i] += __shfl_xor(rs[rg][i], 4);
            rs[rg][i] += __shfl_xor(rs[rg][i], 8);
        }
    if ((l & 15) == 0) {
        #pragma unroll
        for (int rg = 0; rg < 2; ++rg) {
            const int rbase = rb * P_ + w * 32 + rg * 16 + (l >> 4) * 4;
            #pragma unroll
            for (int i = 0; i < 4; ++i)
                rinv[(size_t)bh * N_ + rbase + i] = 1.0f / rs[rg][i];
        }
    }
}

// ---------------------------------------------------------------------------
// Pass 2: colsum[m] = sum_n 2^(q'_n . k'_m) * rinv[n]; out = colsum[m]*v[m,:]
// wg = (bh, 256-col panel); Q' streamed via LDS.
// ---------------------------------------------------------------------------
__global__ __launch_bounds__(512)
void mha_colsum2(const char* __restrict__ qk, const float* __restrict__ rinv,
                 const float* __restrict__ v, float* __restrict__ out)
{
    __shared__ __align__(16) char QT[TILEB];
    __shared__ float rv[T_];
    __shared__ float cs[P_];

    const int t = threadIdx.x, w = t >> 6, l = t & 63;
    const int wid = (blockIdx.x & 7) * 64 + (blockIdx.x >> 3);
    const int bh = wid / NP, cb = wid % NP;

    const char* Qp = qk + (size_t)bh * BHB;
    const char* Kp = qk + (size_t)BH_ * BHB + (size_t)bh * BHB;
    const float* Rg = rinv + (size_t)bh * N_;

    bf16x8 kf[2][2];
    #pragma unroll
    for (int rg = 0; rg < 2; ++rg)
        #pragma unroll
        for (int kh = 0; kh < 2; ++kh) {
            int col = cb * P_ + w * 32 + rg * 16 + (l & 15);
            kf[rg][kh] = *(const bf16x8*)(Kp + swz(col, kh * 4 + (l >> 4)));
        }

    float ca[2] = {0.f, 0.f};

    for (int rt = 0; rt < NT; ++rt) {
        __syncthreads();
        const char* src = Qp + (size_t)rt * TILEB;
        *(bf16x8*)(QT + t * 16)        = *(const bf16x8*)(src + t * 16);
        *(bf16x8*)(QT + 8192 + t * 16) = *(const bf16x8*)(src + 8192 + t * 16);
        if (t < T_) rv[t] = Rg[rt * T_ + t];
        __syncthreads();

        #pragma unroll
        for (int rj = 0; rj < 8; ++rj) {
            const int qr = rj * 16 + (l & 15);
            const int qb = (qr & 127) << 7;
            bf16x8 a0 = *(const bf16x8*)(QT + qb + (((l >> 4) ^ (qr & 7)) << 4));
            bf16x8 a1 = *(const bf16x8*)(QT + qb + (((4 + (l >> 4)) ^ (qr & 7)) << 4));
            float4 r4 = *(const float4*)&rv[rj * 16 + (l >> 4) * 4];
            #pragma unroll
            for (int rg = 0; rg < 2; ++rg) {
                f32x4 c = {0.f, 0.f, 0.f, 0.f};
                c = __builtin_amdgcn_mfma_f32_16x16x32_bf16(a0, kf[rg][0], c, 0, 0, 0);
                c = __builtin_amdgcn_mfma_f32_16x16x32_bf16(a1, kf[rg][1], c, 0, 0, 0);
                ca[rg] += EXP2(c[0]) * r4.x + EXP2(c[1]) * r4.y
                        + EXP2(c[2]) * r4.z + EXP2(c[3]) * r4.w;
            }
        }
    }

    #pragma unroll
    for (int rg = 0; rg < 2; ++rg) {
        ca[rg] += __shfl_xor(ca[rg], 16);
        ca[rg] += __shfl_xor(ca[rg], 32);
    }
    if (l < 16) { cs[w * 32 + l] = ca[0]; cs[w * 32 + 16 + l] = ca[1]; }
    __syncthreads();

    const float4* Vg = (const float4*)(v + ((size_t)bh * N_ + cb * P_) * D_);
    float4* Og = (float4*)(out + ((size_t)bh * N_ + cb * P_) * D_);
    #pragma unroll
    for (int i = 0; i < 8; ++i) {
        int id = i * 512 + t;                // 4096 float4 units
        float s = cs[id >> 4];
        float4 vv = Vg[id];
        float4 o; o.x = vv.x * s; o.y = vv.y * s; o.z = vv.z * s; o.w = vv.w * s;
        Og[id] = o;
    }
}

// ===========================================================================
// Fallback (R2 path) if ws_size is too small for the bf16 staging buffers.
// ===========================================================================
#define FTS 128
#define FNT 16

__device__ __forceinline__ bf16x8 cvt8(const float* p) {
    float4 a = *(const float4*)p;
    float4 b = *(const float4*)(p + 4);
    bf16x8 r;
    r[0] = f2bf(a.x); r[1] = f2bf(a.y); r[2] = f2bf(a.z); r[3] = f2bf(a.w);
    r[4] = f2bf(b.x); r[5] = f2bf(b.y); r[6] = f2bf(b.z); r[7] = f2bf(b.w);
    return r;
}
__device__ __forceinline__ void fstage(char* lds, const float* src, int t) {
    #pragma unroll
    for (int i = 0; i < 2; ++i) {
        int ch = i * 512 + t, r = ch >> 3, cc = ch & 7;
        bf16x8 v = cvt8(src + (size_t)r * D_ + cc * 8);
        *(bf16x8*)(lds + r * 128 + ((cc ^ (r & 7)) << 4)) = v;
    }
}
__device__ __forceinline__ bf16x8 fread(const char* lds, int row, int cc) {
    return *(const bf16x8*)(lds + row * 128 + ((cc ^ (row & 7)) << 4));
}

__global__ __launch_bounds__(512)
void mha_rowsum_fb(const float* __restrict__ q, const float* __restrict__ k,
                   float* __restrict__ rinv)
{
    __shared__ __align__(16) char KT[FTS * 128];
    const int t = threadIdx.x, w = t >> 6, l = t & 63;
    const int bh = blockIdx.x / FNT, rb = blockIdx.x % FNT;
    const float* Qg = q + (size_t)bh * N_ * D_;
    const float* Kg = k + (size_t)bh * N_ * D_;
    const int qrow = rb * FTS + w * 16 + (l & 15);
    bf16x8 af[2];
    #pragma unroll
    for (int kh = 0; kh < 2; ++kh)
        af[kh] = cvt8(Qg + (size_t)qrow * D_ + kh * 32 + (l >> 4) * 8);
    float rs[4] = {0.f, 0.f, 0.f, 0.f};
    for (int ct = 0; ct < FNT; ++ct) {
        __syncthreads();
        fstage(KT, Kg + (size_t)ct * FTS * D_, t);
        __syncthreads();
        #pragma unroll
        for (int cj = 0; cj < 8; ++cj) {
            const int krow = cj * 16 + (l & 15);
            f32x4 c = {0.f, 0.f, 0.f, 0.f};
            #pragma unroll
            for (int kh = 0; kh < 2; ++kh)
                c = __builtin_amdgcn_mfma_f32_16x16x32_bf16(af[kh], fread(KT, krow, kh * 4 + (l >> 4)), c, 0, 0, 0);
            rs[0] += __expf(c[0] * SCALE); rs[1] += __expf(c[1] * SCALE);
            rs[2] += __expf(c[2] * SCALE); rs[3] += __expf(c[3] * SCALE);
        }
    }
    #pragma unroll
    for (int i = 0; i < 4; ++i) {
        rs[i] += __shfl_xor(rs[i], 1); rs[i] += __shfl_xor(rs[i], 2);
        rs[i] += __shfl_xor(rs[i], 4); rs[i] += __shfl_xor(rs[i], 8);
    }
    if ((l & 15) == 0) {
        const int rbase = rb * FTS + w * 16 + (l >> 4) * 4;
        #pragma unroll
        for (int i = 0; i < 4; ++i)
            rinv[(size_t)bh * N_ + rbase + i] = 1.0f / rs[i];
    }
}

__global__ __launch_bounds__(512)
void mha_colsum_fb(const float* __restrict__ q, const float* __restrict__ k,
                   const float* __restrict__ v, const float* __restrict__ rinv,
                   float* __restrict__ out)
{
    __shared__ __align__(16) char QT[FTS * 128];
    __shared__ float rv[FTS];
    __shared__ float cs[FTS];
    const int t = threadIdx.x, w = t >> 6, l = t & 63;
    const int bh = blockIdx.x / FNT, cb = blockIdx.x % FNT;
    const float* Qg = q + (size_t)bh * N_ * D_;
    const float* Kg = k + (size_t)bh * N_ * D_;
    const float* Rg = rinv + (size_t)bh * N_;
    const int kcol = cb * FTS + w * 16 + (l & 15);
    bf16x8 kf[2];
    #pragma unroll
    for (int kh = 0; kh < 2; ++kh)
        kf[kh] = cvt8(Kg + (size_t)kcol * D_ + kh * 32 + (l >> 4) * 8);
    float ca = 0.f;
    for (int rt = 0; rt < FNT; ++rt) {
        __syncthreads();
        fstage(QT, Qg + (size_t)rt * FTS * D_, t);
        if (t < FTS) rv[t] = Rg[rt * FTS + t];
        __syncthreads();
        #pragma unroll
        for (int rj = 0; rj < 8; ++rj) {
            const int qr = rj * 16 + (l & 15);
            f32x4 c = {0.f, 0.f, 0.f, 0.f};
            #pragma unroll
            for (int kh = 0; kh < 2; ++kh)
                c = __builtin_amdgcn_mfma_f32_16x16x32_bf16(fread(QT, qr, kh * 4 + (l >> 4)), kf[kh], c, 0, 0, 0);
            float4 r4 = *(const float4*)&rv[rj * 16 + (l >> 4) * 4];
            ca += __expf(c[0] * SCALE) * r4.x + __expf(c[1] * SCALE) * r4.y
                + __expf(c[2] * SCALE) * r4.z + __expf(c[3] * SCALE) * r4.w;
        }
    }
    ca += __shfl_xor(ca, 16); ca += __shfl_xor(ca, 32);
    if (l < 16) cs[w * 16 + l] = ca;
    __syncthreads();
    const float4* Vg = (const float4*)(v + (size_t)bh * N_ * D_ + (size_t)cb * FTS * D_);
    float4* Og = (float4*)(out + (size_t)bh * N_ * D_ + (size_t)cb * FTS * D_);
    #pragma unroll
    for (int i = 0; i < 4; ++i) {
        int id = i * 512 + t;
        float s = cs[id >> 4];
        float4 vv = Vg[id];
        float4 o; o.x = vv.x * s; o.y = vv.y * s; o.z = vv.z * s; o.w = vv.w * s;
        Og[id] = o;
    }
}

// ---------------------------------------------------------------------------
extern "C" void kernel_launch(void* const* d_in, const int* in_sizes, int n_in,
                              void* d_out, int out_size, void* d_ws, size_t ws_size,
                              hipStream_t stream)
{
    const float* q = (const float*)d_in[0];
    const float* k = (const float*)d_in[1];
    const float* v = (const float*)d_in[2];
    float* out = (float*)d_out;

    const size_t qkBytes = (size_t)2 * BH_ * BHB;          // 32 MB
    const size_t need = qkBytes + (size_t)BH_ * N_ * 4;    // + rinv 512 KB

    if (ws_size >= need) {
        char* qk = (char*)d_ws;
        float* rinv = (float*)(qk + qkBytes);
        mha_convert<<<dim3(2 * BH_ * N_ * 8 / 512), dim3(512), 0, stream>>>(q, k, qk);
        mha_rowsum2<<<dim3(BH_ * NP), dim3(512), 0, stream>>>(qk, rinv);
        mha_colsum2<<<dim3(BH_ * NP), dim3(512), 0, stream>>>(qk, rinv, v, out);
    } else {
        float* rinv = (float*)d_ws;
        mha_rowsum_fb<<<dim3(BH_ * FNT), dim3(512), 0, stream>>>(q, k, rinv);
        mha_colsum_fb<<<dim3(BH_ * FNT), dim3(512), 0, stream>>>(q, k, v, rinv, out);
    }
}